// Round 8
// baseline (123.398 us; speedup 1.0000x reference)
//
#include <hip/hip_runtime.h>
#include <stdint.h>

// out[b,j] = bias[j] + sum_i [ mask*scale_base[i,j]*silu(x[b,i])
//            + mask*scale_fft[i,j]* sum_k ( cos(kx)fc0[j,i,k] + sin(kx)fc1[j,i,k] ) ]
// R21 = R20 structure + latency attack. R20 post-mortem: halving LDS traffic
// changed NOTHING (44.7us = R18's 44.8) -> main is latency/dependency-bound,
// not LDS-BW-bound. Per-SIMD/iter: 6700cy period, MFMA 2480, VALU 2200,
// idle 2100 (per-wave serial chain: sincos + 32-step Chebyshev recurrence +
// ds latency). Changes: (a) dual-chain gen_feat (2x16-step independent
// recurrences, k17 seeded by sincos(17x) -> serial latency ~halved);
// (b) b0 hoisted before gen_feat (16 regs, L2 latency hidden), b1 issued at
// MFMA-phase top (hidden under ks=0 MFMAs). Peak arch liveness ~56 < 64.
// Fixed harness overhead ~64-66us (launch-count-independent, R14-R20).
// Failed escapes (do not retry): R7 VGPR clamp (spill), R8 B-dbuf (-1 blk),
// R9 in-loop fences (L2 inv), R12 full unroll (spill), R15 coop grid.sync
// (~235us), R16 f32-atomic epilogue (64MB RMW), R19 b[2][4]+fb[16] (spill).

#define I_DIM 256
#define O_DIM 256
#define G_DIM 32
#define B_DIM 4096

#define BM 128
#define BN 128
#define KSPLIT 16
#define ICH 16                  // i's per K-chunk
#define PITCH 72                // fallback kernel only

typedef short s8v __attribute__((ext_vector_type(8)));
typedef float f4v __attribute__((ext_vector_type(4)));

__device__ __forceinline__ uint32_t pack2bf16(float a, float b) {  // RNE
  uint32_t ua = __builtin_bit_cast(uint32_t, a);
  uint32_t ub = __builtin_bit_cast(uint32_t, b);
  ua += 0x7FFFu + ((ua >> 16) & 1u);
  ub += 0x7FFFu + ((ub >> 16) & 1u);
  return (ua >> 16) | (ub & 0xFFFF0000u);
}
__device__ __forceinline__ unsigned short bf16_rne(float a) {      // RNE scalar
  uint32_t ua = __builtin_bit_cast(uint32_t, a);
  ua += 0x7FFFu + ((ua >> 16) & 1u);
  return (unsigned short)(ua >> 16);
}
// single-instruction packed f32->bf16 (RNE): lo = bf16(a), hi = bf16(b)
__device__ __forceinline__ uint32_t cvtpk_bf16(float a, float b) {
  uint32_t r;
  asm("v_cvt_pk_bf16_f32 %0, %1, %2" : "=v"(r) : "v"(a), "v"(b));
  return r;
}
__device__ __forceinline__ float silu_f(float v) { return v / (1.0f + __expf(-v)); }

// cos/sin features k=1..32 (one row, one half), streamed to LDS as TWO
// independent 16-step Chebyshev chains (k1-16 from sincos(x); k17-32 seeded
// by sincos(17x), k18 via angle addition). Halves the serial FMA latency.
// Slot layout identical to R17-R20: quad q holds k[8q+1..8q+8].
__device__ __forceinline__ void gen_feat_store(float xv, uint4* Ar, int c0, int xr) {
  const int half = c0 >> 2;                      // c0 = half*4
  float s1, c1, s17, c17;
  __sincosf(xv, &s1, &c1);
  __sincosf(17.f * xv, &s17, &c17);
  const float m2 = 2.f * c1;
  float fA0 = half ? s1 : c1;                            // k=1
  float fA1 = m2 * fA0 - (half ? 0.f : 1.f);             // k=2
  float fB0 = half ? s17 : c17;                          // k=17
  float fB1 = half ? (s17 * c1 + c17 * s1)               // k=18
                   : (c17 * c1 - s17 * s1);
  #pragma unroll
  for (int q = 0; q < 2; ++q) {
    uint32_t wa0 = cvtpk_bf16(fA0, fA1);
    uint32_t wb0 = cvtpk_bf16(fB0, fB1);
    float tA2 = m2 * fA1 - fA0, tB2 = m2 * fB1 - fB0;
    float tA3 = m2 * tA2 - fA1, tB3 = m2 * tB2 - fB1;
    uint32_t wa1 = cvtpk_bf16(tA2, tA3);
    uint32_t wb1 = cvtpk_bf16(tB2, tB3);
    fA0 = m2 * tA3 - tA2;  fB0 = m2 * tB3 - tB2;
    fA1 = m2 * fA0 - tA3;  fB1 = m2 * fB0 - tB3;
    uint32_t wa2 = cvtpk_bf16(fA0, fA1);
    uint32_t wb2 = cvtpk_bf16(fB0, fB1);
    float uA2 = m2 * fA1 - fA0, uB2 = m2 * fB1 - fB0;
    float uA3 = m2 * uA2 - fA1, uB3 = m2 * uB2 - fB1;
    uint32_t wa3 = cvtpk_bf16(uA2, uA3);
    uint32_t wb3 = cvtpk_bf16(uB2, uB3);
    Ar[(c0 + q) ^ xr]     = make_uint4(wa0, wa1, wa2, wa3);   // chain A: k 1-16
    Ar[(c0 + 2 + q) ^ xr] = make_uint4(wb0, wb1, wb2, wb3);   // chain B: k 17-32
    fA0 = m2 * uA3 - uA2;  fB0 = m2 * uB3 - uB2;
    fA1 = m2 * fA0 - uA3;  fB1 = m2 * fB0 - uB3;
  }
}

// ------------------------------------------------ prep: pack B chunk-major
// Slice (i, h): 8KB at Bp + (i*4+h)*4096 shorts, h = 64-col group (j>>6).
// Within a slice: chunk c (0..7; 0-3 cos k[8c..8c+8), 4-7 sin), row r=j&63:
// 16B at (c*64 + r)*8 shorts. Main reads frag (ks,quad,tn,l15) at
// ((ks*4+quad)*64 + tn*16 + l15)*8 -> lanes form 4x256B contiguous segments.
__global__ __launch_bounds__(256) void prep_bs_kernel(
    const float* __restrict__ fc, const float* __restrict__ mask,
    const float* __restrict__ sfft, short* __restrict__ Bp)
{
  const int gid = blockIdx.x * 256 + threadIdx.x;   // 262144 threads
  const int e = gid & 3;                            // (d, k-half)
  const int p = gid >> 2;                           // i*256 + j
  const int i = p >> 8, j = p & 255;
  const int d = e >> 1;
  const int koff = (e & 1) * 16;
  const size_t ij = (size_t)i * O_DIM + j;
  const float sf = sfft[ij] * mask[ij];
  const float* src = fc + ((size_t)d * (O_DIM * I_DIM)
                          + (size_t)j * I_DIM + i) * G_DIM + koff;
  uint32_t w[8];
  #pragma unroll
  for (int q = 0; q < 4; ++q) {
    float4 v = ((const float4*)src)[q];
    w[2*q]   = pack2bf16(v.x * sf, v.y * sf);
    w[2*q+1] = pack2bf16(v.z * sf, v.w * sf);
  }
  const int h = j >> 6, r = j & 63;
  const int cb = d * 4 + (e & 1) * 2;               // first of 2 chunks
  short* dst = Bp + ((size_t)i * 4 + h) * 4096;
  *(uint4*)&dst[(cb * 64 + r) * 8]       = make_uint4(w[0], w[1], w[2], w[3]);
  *(uint4*)&dst[((cb + 1) * 64 + r) * 8] = make_uint4(w[4], w[5], w[6], w[7]);
}

// ------------------------------------------------ main GEMM
// body(it): bar | b0 loads (L2) | gen_feat_store A[nxt] (hides b0 latency,
// dual-chain) | setprio(1): b1 loads, a-reads ks0, MFMA ks0 (hides b1),
// a-reads ks1, MFMA ks1 | setprio(0). One barrier per iteration.
__global__ __launch_bounds__(256, 4) void kan_main8(
    const float* __restrict__ x,
    const short* __restrict__ Bp,
    const float* __restrict__ mask,
    const float* __restrict__ scale_base,
    unsigned short* __restrict__ partial) // (16, 4096, 256) bf16
{
  __shared__ short A_lds[2][BM * 64];     // 32 KB total: A double buffer

  const int tid = threadIdx.x;
  const int bx  = blockIdx.x;
  const int kc  = bx & 15;                // XCD affinity: Bp slice L2-resident
  const int bn  = (bx >> 4) & 1;
  const int bm  = bx >> 5;
  const int i0  = kc * ICH;

  const int lane = tid & 63;
  const int wave = tid >> 6;
  const int wm   = wave & 1;
  const int wn   = wave >> 1;
  const int l15  = lane & 15;
  const int quad = lane >> 4;

  f4v acc[4][4];
  #pragma unroll
  for (int a = 0; a < 4; ++a)
    #pragma unroll
    for (int b = 0; b < 4; ++b)
      acc[a][b] = (f4v){0.f, 0.f, 0.f, 0.f};

  const int row  = tid >> 1;
  const int half = tid & 1;
  const int mg   = bm * BM + row;
  const int jg   = bn * BN + row;
  const int xr   = row & 7;

  const float* xrow = x + (size_t)mg * I_DIM + i0;
  const int c0 = half * 4;                // this thread's 4 A-chunks

  // B base for this wave's 64-col slice; +16384 shorts per i
  const short* bbase = Bp + ((size_t)i0 * 4 + (size_t)(bn * 2 + wn)) * 4096;

  // prologue: stage A(0) into buf 0
  gen_feat_store(xrow[0], (uint4*)&A_lds[0][row * 64], c0, xr);
  float xnxt = xrow[1];

  for (int it = 0; it < ICH; ++it) {
    __syncthreads();                      // A[it&1] writes visible

    const short* bsl = bbase + (size_t)it * 16384;

    // b0 (ks=0): issue BEFORE gen_feat -> ~200cy L2 latency hides under it
    s8v b0[4];
    #pragma unroll
    for (int tn = 0; tn < 4; ++tn)
      b0[tn] = *(const s8v*)&bsl[(quad * 64 + tn * 16 + l15) * 8];

    // stage A(it+1) into alternate buffer (dual-chain, low liveness)
    if (it + 1 < ICH) {
      gen_feat_store(xnxt, (uint4*)&A_lds[(it + 1) & 1][row * 64], c0, xr);
      if (it + 2 < ICH) xnxt = xrow[it + 2];
    }

    const short* Ac = &A_lds[it & 1][0];
    __builtin_amdgcn_s_setprio(1);

    // b1 (ks=1): issue now; latency hides under ks=0's 16 MFMAs
    s8v b1[4];
    #pragma unroll
    for (int tn = 0; tn < 4; ++tn)
      b1[tn] = *(const s8v*)&bsl[((4 + quad) * 64 + tn * 16 + l15) * 8];

    {
      s8v a[4];
      #pragma unroll
      for (int tm = 0; tm < 4; ++tm) {
        const int r = wm * 64 + tm * 16 + l15;
        a[tm] = *(const s8v*)&Ac[r * 64 + ((quad ^ (r & 7)) * 8)];
      }
      #pragma unroll
      for (int tm = 0; tm < 4; ++tm)
        #pragma unroll
        for (int tn = 0; tn < 4; ++tn)
          acc[tm][tn] = __builtin_amdgcn_mfma_f32_16x16x32_bf16(a[tm], b0[tn], acc[tm][tn], 0, 0, 0);
    }
    {
      s8v a[4];
      #pragma unroll
      for (int tm = 0; tm < 4; ++tm) {
        const int r = wm * 64 + tm * 16 + l15;
        a[tm] = *(const s8v*)&Ac[r * 64 + (((4 + quad) ^ (r & 7)) * 8)];
      }
      #pragma unroll
      for (int tm = 0; tm < 4; ++tm)
        #pragma unroll
        for (int tn = 0; tn < 4; ++tn)
          acc[tm][tn] = __builtin_amdgcn_mfma_f32_16x16x32_bf16(a[tm], b1[tn], acc[tm][tn], 0, 0, 0);
    }
    __builtin_amdgcn_s_setprio(0);
  }

  // ---------------- base tile: K=32 (16 silu features + 16 zeros)
  // A-stage in A_lds[0], B-stage in A_lds[1]
  __syncthreads();
  {
    const float* xb = xrow + half * 8;
    float4 v0 = ((const float4*)xb)[0];
    float4 v1 = ((const float4*)xb)[1];
    uint32_t a0 = pack2bf16(silu_f(v0.x), silu_f(v0.y));
    uint32_t a1 = pack2bf16(silu_f(v0.z), silu_f(v0.w));
    uint32_t a2 = pack2bf16(silu_f(v1.x), silu_f(v1.y));
    uint32_t a3 = pack2bf16(silu_f(v1.z), silu_f(v1.w));
    uint4* Arow = (uint4*)&A_lds[0][row * 64];
    Arow[half ^ xr]       = make_uint4(a0, a1, a2, a3);
    Arow[(2 + half) ^ xr] = make_uint4(0, 0, 0, 0);

    uint32_t w[4];
    #pragma unroll
    for (int p = 0; p < 4; ++p) {
      const int ia = i0 + half * 8 + 2 * p;
      const size_t o0 = (size_t)ia * O_DIM + jg;
      const size_t o1 = o0 + O_DIM;
      w[p] = pack2bf16(scale_base[o0] * mask[o0], scale_base[o1] * mask[o1]);
    }
    uint4* Brow = (uint4*)&A_lds[1][row * 64];
    Brow[half ^ xr]       = make_uint4(w[0], w[1], w[2], w[3]);
    Brow[(2 + half) ^ xr] = make_uint4(0, 0, 0, 0);
  }
  __syncthreads();
  {
    __builtin_amdgcn_s_setprio(1);
    s8v a[4], b[4];
    #pragma unroll
    for (int tm = 0; tm < 4; ++tm) {
      const int r = wm * 64 + tm * 16 + l15;
      a[tm] = *(const s8v*)&A_lds[0][r * 64 + ((quad ^ (r & 7)) * 8)];
    }
    #pragma unroll
    for (int tn = 0; tn < 4; ++tn) {
      const int r = wn * 64 + tn * 16 + l15;
      b[tn] = *(const s8v*)&A_lds[1][r * 64 + ((quad ^ (r & 7)) * 8)];
    }
    #pragma unroll
    for (int tm = 0; tm < 4; ++tm)
      #pragma unroll
      for (int tn = 0; tn < 4; ++tn)
        acc[tm][tn] = __builtin_amdgcn_mfma_f32_16x16x32_bf16(a[tm], b[tn], acc[tm][tn], 0, 0, 0);
    __builtin_amdgcn_s_setprio(0);
  }

  // ---------------- epilogue: coalesced bf16 partial stores (RNE, once/block)
  unsigned short* pbase = partial + (size_t)kc * B_DIM * O_DIM;
  #pragma unroll
  for (int tm = 0; tm < 4; ++tm) {
    #pragma unroll
    for (int tn = 0; tn < 4; ++tn) {
      const int n_g = bn * BN + wn * 64 + tn * 16 + l15;
      f4v v = acc[tm][tn];
      #pragma unroll
      for (int r = 0; r < 4; ++r) {
        const int m_g = bm * BM + wm * 64 + tm * 16 + quad * 4 + r;
        pbase[(size_t)m_g * O_DIM + n_g] = bf16_rne(v[r]);
      }
    }
  }
}

// ------------------------------------------------ reduce (bf16 partials)
__global__ __launch_bounds__(256) void reduce_kernel(
    const unsigned short* __restrict__ partial, const float* __restrict__ bias,
    float* __restrict__ out)
{
  const int g  = blockIdx.x * 256 + threadIdx.x;   // 131072 threads
  const int m  = g >> 5;
  const int n8 = (g & 31) << 3;
  const unsigned short* p = partial + (size_t)m * O_DIM + n8;

  float acc[8];
  {
    float4 b0 = ((const float4*)(bias + n8))[0];
    float4 b1 = ((const float4*)(bias + n8))[1];
    acc[0] = b0.x; acc[1] = b0.y; acc[2] = b0.z; acc[3] = b0.w;
    acc[4] = b1.x; acc[5] = b1.y; acc[6] = b1.z; acc[7] = b1.w;
  }
  #pragma unroll
  for (int kc = 0; kc < KSPLIT; ++kc) {
    const uint4 v = *(const uint4*)(p + (size_t)kc * (B_DIM * O_DIM));
    acc[0] += __builtin_bit_cast(float, v.x << 16);
    acc[1] += __builtin_bit_cast(float, v.x & 0xFFFF0000u);
    acc[2] += __builtin_bit_cast(float, v.y << 16);
    acc[3] += __builtin_bit_cast(float, v.y & 0xFFFF0000u);
    acc[4] += __builtin_bit_cast(float, v.z << 16);
    acc[5] += __builtin_bit_cast(float, v.z & 0xFFFF0000u);
    acc[6] += __builtin_bit_cast(float, v.w << 16);
    acc[7] += __builtin_bit_cast(float, v.w & 0xFFFF0000u);
  }
  float* o = out + (size_t)m * O_DIM + n8;
  ((float4*)o)[0] = make_float4(acc[0], acc[1], acc[2], acc[3]);
  ((float4*)o)[1] = make_float4(acc[4], acc[5], acc[6], acc[7]);
}

// ================================================ ws-free atomic fallback (R2)
__device__ __forceinline__ void gen_feat(float xv, int half, uint32_t* fb) {
  float s, c;
  __sincosf(xv, &s, &c);
  const float m2 = 2.f * c;
  float f0 = half ? s : c;
  float f1 = m2 * f0 - (half ? 0.f : 1.f);
  fb[0] = cvtpk_bf16(f0, f1);
  #pragma unroll
  for (int p = 1; p < 16; ++p) {
    float f2 = m2 * f1 - f0;
    float f3 = m2 * f2 - f1;
    fb[p] = cvtpk_bf16(f2, f3);
    f0 = f2; f1 = f3;
  }
}

__global__ __launch_bounds__(256, 4) void kan_fft_fallback(
    const float* __restrict__ x, const float* __restrict__ fc,
    const float* __restrict__ bias, const float* __restrict__ mask,
    const float* __restrict__ scale_base, const float* __restrict__ scale_fft,
    float* __restrict__ out)
{
  __shared__ short A_lds[BM * PITCH];
  __shared__ short B_lds[BN * PITCH];

  const int tid = threadIdx.x;
  const int bx  = blockIdx.x;
  const int kc  = bx & 15;
  const int bn  = (bx >> 4) & 1;
  const int bm  = bx >> 5;
  const int i0  = kc * ICH;

  const int lane = tid & 63;
  const int wave = tid >> 6;
  const int wm   = wave & 1;
  const int wn   = wave >> 1;
  const int l15  = lane & 15;
  const int kgrp = (lane >> 4) * 8;

  f4v acc[4][4];
  #pragma unroll
  for (int a = 0; a < 4; ++a)
    #pragma unroll
    for (int b = 0; b < 4; ++b)
      acc[a][b] = (f4v){0.f, 0.f, 0.f, 0.f};

  const int row  = tid >> 1;
  const int half = tid & 1;
  const int mg   = bm * BM + row;
  const int jg   = bn * BN + row;

  const float* xrow   = x + (size_t)mg * I_DIM + i0;
  const float* fcbase = fc + (size_t)half * (O_DIM * I_DIM * G_DIM)
                           + ((size_t)jg * I_DIM + i0) * G_DIM;
  uint32_t* Arow = (uint32_t*)&A_lds[row * PITCH + half * 32];
  uint32_t* Brow = (uint32_t*)&B_lds[row * PITCH + half * 32];

  for (int it = 0; it < ICH; ++it) {
    __syncthreads();
    {
      uint32_t fb[16];
      gen_feat(xrow[it], half, fb);
      ((uint4*)Arow)[0] = make_uint4(fb[0],  fb[1],  fb[2],  fb[3]);
      ((uint4*)Arow)[1] = make_uint4(fb[4],  fb[5],  fb[6],  fb[7]);
      ((uint4*)Arow)[2] = make_uint4(fb[8],  fb[9],  fb[10], fb[11]);
      ((uint4*)Arow)[3] = make_uint4(fb[12], fb[13], fb[14], fb[15]);
    }
    {
      const int i = i0 + it;
      const size_t ij = (size_t)i * O_DIM + jg;
      const float sf  = scale_fft[ij] * mask[ij];
      const float* src = fcbase + it * G_DIM;
      uint32_t wb[16];
      #pragma unroll
      for (int q = 0; q < 8; ++q) {
        float4 v = ((const float4*)src)[q];
        wb[2*q]   = pack2bf16(v.x * sf, v.y * sf);
        wb[2*q+1] = pack2bf16(v.z * sf, v.w * sf);
      }
      ((uint4*)Brow)[0] = make_uint4(wb[0],  wb[1],  wb[2],  wb[3]);
      ((uint4*)Brow)[1] = make_uint4(wb[4],  wb[5],  wb[6],  wb[7]);
      ((uint4*)Brow)[2] = make_uint4(wb[8],  wb[9],  wb[10], wb[11]);
      ((uint4*)Brow)[3] = make_uint4(wb[12], wb[13], wb[14], wb[15]);
    }
    __syncthreads();
    #pragma unroll
    for (int ks = 0; ks < 2; ++ks) {
      s8v a[4], b[4];
      #pragma unroll
      for (int tm = 0; tm < 4; ++tm)
        a[tm] = *(const s8v*)&A_lds[(wm * 64 + tm * 16 + l15) * PITCH + ks * 32 + kgrp];
      #pragma unroll
      for (int tn = 0; tn < 4; ++tn)
        b[tn] = *(const s8v*)&B_lds[(wn * 64 + tn * 16 + l15) * PITCH + ks * 32 + kgrp];
      #pragma unroll
      for (int tm = 0; tm < 4; ++tm)
        #pragma unroll
        for (int tn = 0; tn < 4; ++tn)
          acc[tm][tn] = __builtin_amdgcn_mfma_f32_16x16x32_bf16(a[tm], b[tn], acc[tm][tn], 0, 0, 0);
    }
  }

  __syncthreads();
  {
    const float* xb = xrow + half * 8;
    float4 v0 = ((const float4*)xb)[0];
    float4 v1 = ((const float4*)xb)[1];
    uint32_t a0 = pack2bf16(silu_f(v0.x), silu_f(v0.y));
    uint32_t a1 = pack2bf16(silu_f(v0.z), silu_f(v0.w));
    uint32_t a2 = pack2bf16(silu_f(v1.x), silu_f(v1.y));
    uint32_t a3 = pack2bf16(silu_f(v1.z), silu_f(v1.w));
    ((uint4*)&A_lds[row * PITCH + half * 8])[0]      = make_uint4(a0, a1, a2, a3);
    ((uint4*)&A_lds[row * PITCH + 16 + half * 8])[0] = make_uint4(0, 0, 0, 0);
    uint32_t w[4];
    #pragma unroll
    for (int p = 0; p < 4; ++p) {
      const int ia = i0 + half * 8 + 2 * p;
      const size_t o0 = (size_t)ia * O_DIM + jg;
      const size_t o1 = o0 + O_DIM;
      w[p] = pack2bf16(scale_base[o0] * mask[o0], scale_base[o1] * mask[o1]);
    }
    ((uint4*)&B_lds[row * PITCH + half * 8])[0]      = make_uint4(w[0], w[1], w[2], w[3]);
    ((uint4*)&B_lds[row * PITCH + 16 + half * 8])[0] = make_uint4(0, 0, 0, 0);
  }
  __syncthreads();
  {
    s8v a[4], b[4];
    #pragma unroll
    for (int tm = 0; tm < 4; ++tm)
      a[tm] = *(const s8v*)&A_lds[(wm * 64 + tm * 16 + l15) * PITCH + kgrp];
    #pragma unroll
    for (int tn = 0; tn < 4; ++tn)
      b[tn] = *(const s8v*)&B_lds[(wn * 64 + tn * 16 + l15) * PITCH + kgrp];
    #pragma unroll
    for (int tm = 0; tm < 4; ++tm)
      #pragma unroll
      for (int tn = 0; tn < 4; ++tn)
        acc[tm][tn] = __builtin_amdgcn_mfma_f32_16x16x32_bf16(a[tm], b[tn], acc[tm][tn], 0, 0, 0);
  }

  const int quad = lane >> 4;
  #pragma unroll
  for (int tm = 0; tm < 4; ++tm) {
    #pragma unroll
    for (int tn = 0; tn < 4; ++tn) {
      const int n_g = bn * BN + wn * 64 + tn * 16 + l15;
      f4v v = acc[tm][tn];
      #pragma unroll
      for (int r = 0; r < 4; ++r) {
        const int m_g = bm * BM + wm * 64 + tm * 16 + quad * 4 + r;
        float val = v[r];
        if (kc == 0) val += bias[n_g];
        atomicAdd(&out[(size_t)m_g * O_DIM + n_g], val);
      }
    }
  }
}

extern "C" void kernel_launch(void* const* d_in, const int* in_sizes, int n_in,
                              void* d_out, int out_size, void* d_ws, size_t ws_size,
                              hipStream_t stream) {
  const float* x          = (const float*)d_in[0];
  const float* fc         = (const float*)d_in[1];
  const float* bias       = (const float*)d_in[2];
  const float* mask       = (const float*)d_in[3];
  const float* scale_base = (const float*)d_in[4];
  const float* scale_fft  = (const float*)d_in[5];
  float* out = (float*)d_out;

  const size_t BP_B    = (size_t)I_DIM * O_DIM * 64 * 2;        //  8,388,608
  const size_t PARTH_B = (size_t)KSPLIT * B_DIM * O_DIM * 2;    // 33,554,432

  if (ws_size >= BP_B + PARTH_B) {
    short*          Bp      = (short*)d_ws;
    unsigned short* partial = (unsigned short*)((char*)d_ws + BP_B);
    prep_bs_kernel<<<dim3(1024), dim3(256), 0, stream>>>(fc, mask, scale_fft, Bp);
    kan_main8<<<dim3(1024), dim3(256), 0, stream>>>(x, Bp, mask, scale_base, partial);
    reduce_kernel<<<dim3(512), dim3(256), 0, stream>>>(partial, bias, out);
  } else {
    hipMemsetAsync(d_out, 0, (size_t)out_size * sizeof(float), stream);
    kan_fft_fallback<<<dim3(1024), dim3(256), 0, stream>>>(
        x, fc, bias, mask, scale_base, scale_fft, out);
  }
}

// Round 9
// 121.406 us; speedup vs baseline: 1.0164x; 1.0164x over previous
//
#include <hip/hip_runtime.h>
#include <stdint.h>

// out[b,j] = bias[j] + sum_i [ mask*scale_base[i,j]*silu(x[b,i])
//            + mask*scale_fft[i,j]* sum_k ( cos(kx)fc0[j,i,k] + sin(kx)fc1[j,i,k] ) ]
// R22: kill the bn-duplication of gen_feat. R18/R20/R21 all converge at
// ~44.5us main (invariant across staging/barriers/LDS-traffic/chain-length)
// -> latency bind at 4 waves/SIMD with VALU ~14.7us aggregate (gen_feat).
// New geometry: block 128x256 (bn gone), 512 thr = 8 waves (2wm x 4wn),
// wave tile 64x64 (per-wave schedule and Bp layout UNCHANGED; h=j>>6 already
// yields 4 col-slices). Grid 512 = 16kc x 32bm = 2 blocks/CU; 16 waves/CU,
// 128 VGPR/wave - same occupancy, but total gen_feat work HALVES and
// per-thread chain halves (4 thr/row, one 16-k chain each).
// Base tile: two-pass B-stage (256 cols through 16KB buffer), one-time cost.
// Fixed harness overhead ~64-66us (launch-count-independent, R14-R21).
// Failed escapes (do not retry): R7 VGPR clamp (spill), R8 B-dbuf (-1 blk),
// R9 in-loop fences (L2 inv), R12 full unroll (spill), R15 coop grid.sync
// (~235us), R16 f32-atomic epilogue (64MB RMW), R19 b[2][4]+fb[16] (spill).

#define I_DIM 256
#define O_DIM 256
#define G_DIM 32
#define B_DIM 4096

#define BM 128
#define BN 256                  // R22: full width per block
#define KSPLIT 16
#define ICH 16                  // i's per K-chunk
#define PITCH 72                // fallback kernel only

typedef short s8v __attribute__((ext_vector_type(8)));
typedef float f4v __attribute__((ext_vector_type(4)));

__device__ __forceinline__ uint32_t pack2bf16(float a, float b) {  // RNE
  uint32_t ua = __builtin_bit_cast(uint32_t, a);
  uint32_t ub = __builtin_bit_cast(uint32_t, b);
  ua += 0x7FFFu + ((ua >> 16) & 1u);
  ub += 0x7FFFu + ((ub >> 16) & 1u);
  return (ua >> 16) | (ub & 0xFFFF0000u);
}
__device__ __forceinline__ unsigned short bf16_rne(float a) {      // RNE scalar
  uint32_t ua = __builtin_bit_cast(uint32_t, a);
  ua += 0x7FFFu + ((ua >> 16) & 1u);
  return (unsigned short)(ua >> 16);
}
// single-instruction packed f32->bf16 (RNE): lo = bf16(a), hi = bf16(b)
__device__ __forceinline__ uint32_t cvtpk_bf16(float a, float b) {
  uint32_t r;
  asm("v_cvt_pk_bf16_f32 %0, %1, %2" : "=v"(r) : "v"(a), "v"(b));
  return r;
}
__device__ __forceinline__ float silu_f(float v) { return v / (1.0f + __expf(-v)); }

// ONE 16-k Chebyshev chain (half = cos/sin, chain = k1-16 / k17-32), streamed
// to 2 LDS slots. Same FMA/cvt sequence as R21's dual-chain -> bit-identical.
__device__ __forceinline__ void gen_feat_chain(float xv, int half, int chain,
                                               uint4* Ar, int c0, int xr) {
  float s1, c1;
  __sincosf(xv, &s1, &c1);
  const float m2 = 2.f * c1;
  float f0, f1;
  if (chain == 0) {
    f0 = half ? s1 : c1;                          // k=1
    f1 = m2 * f0 - (half ? 0.f : 1.f);            // k=2
  } else {
    float s17, c17;
    __sincosf(17.f * xv, &s17, &c17);
    f0 = half ? s17 : c17;                        // k=17
    f1 = half ? (s17 * c1 + c17 * s1)             // k=18 (angle add)
              : (c17 * c1 - s17 * s1);
  }
  const int sb = c0 + 2 * chain;
  #pragma unroll
  for (int q = 0; q < 2; ++q) {
    uint32_t w0 = cvtpk_bf16(f0, f1);
    float t2 = m2 * f1 - f0;
    float t3 = m2 * t2 - f1;
    uint32_t w1 = cvtpk_bf16(t2, t3);
    f0 = m2 * t3 - t2;
    f1 = m2 * f0 - t3;
    uint32_t w2 = cvtpk_bf16(f0, f1);
    float u2 = m2 * f1 - f0;
    float u3 = m2 * u2 - f1;
    uint32_t w3 = cvtpk_bf16(u2, u3);
    Ar[(sb + q) ^ xr] = make_uint4(w0, w1, w2, w3);
    f0 = m2 * u3 - u2;
    f1 = m2 * f0 - u3;
  }
}

// ------------------------------------------------ prep: pack B chunk-major
// Slice (i, h): 8KB at Bp + (i*4+h)*4096 shorts, h = 64-col group (j>>6).
// Within a slice: chunk c (0..7; 0-3 cos k[8c..8c+8), 4-7 sin), row r=j&63:
// 16B at (c*64 + r)*8 shorts. Main reads frag (ks,quad,tn,l15) at
// ((ks*4+quad)*64 + tn*16 + l15)*8 -> lanes form 4x256B contiguous segments.
__global__ __launch_bounds__(256) void prep_bs_kernel(
    const float* __restrict__ fc, const float* __restrict__ mask,
    const float* __restrict__ sfft, short* __restrict__ Bp)
{
  const int gid = blockIdx.x * 256 + threadIdx.x;   // 262144 threads
  const int e = gid & 3;                            // (d, k-half)
  const int p = gid >> 2;                           // i*256 + j
  const int i = p >> 8, j = p & 255;
  const int d = e >> 1;
  const int koff = (e & 1) * 16;
  const size_t ij = (size_t)i * O_DIM + j;
  const float sf = sfft[ij] * mask[ij];
  const float* src = fc + ((size_t)d * (O_DIM * I_DIM)
                          + (size_t)j * I_DIM + i) * G_DIM + koff;
  uint32_t w[8];
  #pragma unroll
  for (int q = 0; q < 4; ++q) {
    float4 v = ((const float4*)src)[q];
    w[2*q]   = pack2bf16(v.x * sf, v.y * sf);
    w[2*q+1] = pack2bf16(v.z * sf, v.w * sf);
  }
  const int h = j >> 6, r = j & 63;
  const int cb = d * 4 + (e & 1) * 2;               // first of 2 chunks
  short* dst = Bp + ((size_t)i * 4 + h) * 4096;
  *(uint4*)&dst[(cb * 64 + r) * 8]       = make_uint4(w[0], w[1], w[2], w[3]);
  *(uint4*)&dst[((cb + 1) * 64 + r) * 8] = make_uint4(w[4], w[5], w[6], w[7]);
}

// ------------------------------------------------ main GEMM (R22 geometry)
// 512 thr = 8 waves (wm=wave&1, wn=wave>>1 in 0..3), block 128x256.
// body(it): bar | b0 loads (L2) | gen_feat_chain A[nxt] (1 chain/thread) |
// setprio(1): b1 loads, a ks0 + MFMA b0, a ks1 + MFMA b1 | setprio(0).
__global__ __launch_bounds__(512, 4) void kan_main9(
    const float* __restrict__ x,
    const short* __restrict__ Bp,
    const float* __restrict__ mask,
    const float* __restrict__ scale_base,
    unsigned short* __restrict__ partial) // (16, 4096, 256) bf16
{
  __shared__ short A_lds[2][BM * 64];     // 32 KB total: A double buffer

  const int tid = threadIdx.x;
  const int bx  = blockIdx.x;             // 512 blocks
  const int kc  = bx & 15;                // XCD affinity: Bp slice L2-resident
  const int bm  = bx >> 4;                // 0..31
  const int i0  = kc * ICH;

  const int lane = tid & 63;
  const int wave = tid >> 6;              // 0..7
  const int wm   = wave & 1;
  const int wn   = wave >> 1;             // 0..3
  const int l15  = lane & 15;
  const int quad = lane >> 4;

  f4v acc[4][4];
  #pragma unroll
  for (int a = 0; a < 4; ++a)
    #pragma unroll
    for (int b = 0; b < 4; ++b)
      acc[a][b] = (f4v){0.f, 0.f, 0.f, 0.f};

  const int row   = tid >> 2;             // 0..127
  const int q4    = tid & 3;              // (half, chain)
  const int half  = q4 & 1;
  const int chain = q4 >> 1;
  const int mg    = bm * BM + row;
  const int xr    = row & 7;
  const int c0    = half * 4;

  const float* xrow = x + (size_t)mg * I_DIM + i0;

  // B base for this wave's 64-col slice (h = wn); +16384 shorts per i
  const short* bbase = Bp + ((size_t)i0 * 4 + (size_t)wn) * 4096;

  // prologue: stage A(0) into buf 0
  gen_feat_chain(xrow[0], half, chain, (uint4*)&A_lds[0][row * 64], c0, xr);
  float xnxt = xrow[1];

  for (int it = 0; it < ICH; ++it) {
    __syncthreads();                      // A[it&1] writes visible

    const short* bsl = bbase + (size_t)it * 16384;

    // b0 (ks=0): issue BEFORE gen_feat -> L2 latency hides under it
    s8v b0[4];
    #pragma unroll
    for (int tn = 0; tn < 4; ++tn)
      b0[tn] = *(const s8v*)&bsl[(quad * 64 + tn * 16 + l15) * 8];

    // stage A(it+1): one 16-k chain per thread (half the R21 serial length)
    if (it + 1 < ICH) {
      gen_feat_chain(xnxt, half, chain, (uint4*)&A_lds[(it + 1) & 1][row * 64], c0, xr);
      if (it + 2 < ICH) xnxt = xrow[it + 2];
    }

    const short* Ac = &A_lds[it & 1][0];
    __builtin_amdgcn_s_setprio(1);

    // b1 (ks=1): latency hides under ks=0's 16 MFMAs
    s8v b1[4];
    #pragma unroll
    for (int tn = 0; tn < 4; ++tn)
      b1[tn] = *(const s8v*)&bsl[((4 + quad) * 64 + tn * 16 + l15) * 8];

    {
      s8v a[4];
      #pragma unroll
      for (int tm = 0; tm < 4; ++tm) {
        const int r = wm * 64 + tm * 16 + l15;
        a[tm] = *(const s8v*)&Ac[r * 64 + ((quad ^ (r & 7)) * 8)];
      }
      #pragma unroll
      for (int tm = 0; tm < 4; ++tm)
        #pragma unroll
        for (int tn = 0; tn < 4; ++tn)
          acc[tm][tn] = __builtin_amdgcn_mfma_f32_16x16x32_bf16(a[tm], b0[tn], acc[tm][tn], 0, 0, 0);
    }
    {
      s8v a[4];
      #pragma unroll
      for (int tm = 0; tm < 4; ++tm) {
        const int r = wm * 64 + tm * 16 + l15;
        a[tm] = *(const s8v*)&Ac[r * 64 + (((4 + quad) ^ (r & 7)) * 8)];
      }
      #pragma unroll
      for (int tm = 0; tm < 4; ++tm)
        #pragma unroll
        for (int tn = 0; tn < 4; ++tn)
          acc[tm][tn] = __builtin_amdgcn_mfma_f32_16x16x32_bf16(a[tm], b1[tn], acc[tm][tn], 0, 0, 0);
    }
    __builtin_amdgcn_s_setprio(0);
  }

  // ---------------- base tile: K=32 (16 silu features + 16 zeros)
  // A-base in A_lds[0] (128 rows); B-scale in A_lds[1], two passes of 128
  // cols each (BN=256 doesn't fit the 16KB buffer at once).
  __syncthreads();                        // all waves done reading A_lds[1]
  {
    // A-base: 4 threads/row, thread q4: q4<2 -> silu uint4, q4>=2 -> zeros
    uint4 val = make_uint4(0, 0, 0, 0);
    if (q4 < 2) {
      const float* xb = xrow + q4 * 8;
      float4 v0 = ((const float4*)xb)[0];
      float4 v1 = ((const float4*)xb)[1];
      val = make_uint4(pack2bf16(silu_f(v0.x), silu_f(v0.y)),
                       pack2bf16(silu_f(v0.z), silu_f(v0.w)),
                       pack2bf16(silu_f(v1.x), silu_f(v1.y)),
                       pack2bf16(silu_f(v1.z), silu_f(v1.w)));
    }
    ((uint4*)&A_lds[0][row * 64])[q4 ^ xr] = val;
  }
  #pragma unroll
  for (int h2 = 0; h2 < 2; ++h2) {
    {
      // B-scale stage: jg = h2*128 + row, 4 threads/row
      const int jg = h2 * 128 + row;
      uint4 val = make_uint4(0, 0, 0, 0);
      if (q4 < 2) {
        uint32_t w[4];
        #pragma unroll
        for (int p = 0; p < 4; ++p) {
          const int ia = i0 + q4 * 8 + 2 * p;
          const size_t o0 = (size_t)ia * O_DIM + jg;
          const size_t o1 = o0 + O_DIM;
          w[p] = pack2bf16(scale_base[o0] * mask[o0], scale_base[o1] * mask[o1]);
        }
        val = make_uint4(w[0], w[1], w[2], w[3]);
      }
      ((uint4*)&A_lds[1][row * 64])[q4 ^ xr] = val;
    }
    __syncthreads();
    if ((wn >> 1) == h2) {
      __builtin_amdgcn_s_setprio(1);
      s8v a[4], b[4];
      #pragma unroll
      for (int tm = 0; tm < 4; ++tm) {
        const int r = wm * 64 + tm * 16 + l15;
        a[tm] = *(const s8v*)&A_lds[0][r * 64 + ((quad ^ (r & 7)) * 8)];
      }
      #pragma unroll
      for (int tn = 0; tn < 4; ++tn) {
        const int r = (wn & 1) * 64 + tn * 16 + l15;
        b[tn] = *(const s8v*)&A_lds[1][r * 64 + ((quad ^ (r & 7)) * 8)];
      }
      #pragma unroll
      for (int tm = 0; tm < 4; ++tm)
        #pragma unroll
        for (int tn = 0; tn < 4; ++tn)
          acc[tm][tn] = __builtin_amdgcn_mfma_f32_16x16x32_bf16(a[tm], b[tn], acc[tm][tn], 0, 0, 0);
      __builtin_amdgcn_s_setprio(0);
    }
    __syncthreads();                      // pass MFMA done before re-stage
  }

  // ---------------- epilogue: coalesced bf16 partial stores (RNE, once/block)
  unsigned short* pbase = partial + (size_t)kc * B_DIM * O_DIM;
  #pragma unroll
  for (int tm = 0; tm < 4; ++tm) {
    #pragma unroll
    for (int tn = 0; tn < 4; ++tn) {
      const int n_g = wn * 64 + tn * 16 + l15;
      f4v v = acc[tm][tn];
      #pragma unroll
      for (int r = 0; r < 4; ++r) {
        const int m_g = bm * BM + wm * 64 + tm * 16 + quad * 4 + r;
        pbase[(size_t)m_g * O_DIM + n_g] = bf16_rne(v[r]);
      }
    }
  }
}

// ------------------------------------------------ reduce (bf16 partials)
__global__ __launch_bounds__(256) void reduce_kernel(
    const unsigned short* __restrict__ partial, const float* __restrict__ bias,
    float* __restrict__ out)
{
  const int g  = blockIdx.x * 256 + threadIdx.x;   // 131072 threads
  const int m  = g >> 5;
  const int n8 = (g & 31) << 3;
  const unsigned short* p = partial + (size_t)m * O_DIM + n8;

  float acc[8];
  {
    float4 b0 = ((const float4*)(bias + n8))[0];
    float4 b1 = ((const float4*)(bias + n8))[1];
    acc[0] = b0.x; acc[1] = b0.y; acc[2] = b0.z; acc[3] = b0.w;
    acc[4] = b1.x; acc[5] = b1.y; acc[6] = b1.z; acc[7] = b1.w;
  }
  #pragma unroll
  for (int kc = 0; kc < KSPLIT; ++kc) {
    const uint4 v = *(const uint4*)(p + (size_t)kc * (B_DIM * O_DIM));
    acc[0] += __builtin_bit_cast(float, v.x << 16);
    acc[1] += __builtin_bit_cast(float, v.x & 0xFFFF0000u);
    acc[2] += __builtin_bit_cast(float, v.y << 16);
    acc[3] += __builtin_bit_cast(float, v.y & 0xFFFF0000u);
    acc[4] += __builtin_bit_cast(float, v.z << 16);
    acc[5] += __builtin_bit_cast(float, v.z & 0xFFFF0000u);
    acc[6] += __builtin_bit_cast(float, v.w << 16);
    acc[7] += __builtin_bit_cast(float, v.w & 0xFFFF0000u);
  }
  float* o = out + (size_t)m * O_DIM + n8;
  ((float4*)o)[0] = make_float4(acc[0], acc[1], acc[2], acc[3]);
  ((float4*)o)[1] = make_float4(acc[4], acc[5], acc[6], acc[7]);
}

// ================================================ ws-free atomic fallback (R2)
__device__ __forceinline__ void gen_feat(float xv, int half, uint32_t* fb) {
  float s, c;
  __sincosf(xv, &s, &c);
  const float m2 = 2.f * c;
  float f0 = half ? s : c;
  float f1 = m2 * f0 - (half ? 0.f : 1.f);
  fb[0] = cvtpk_bf16(f0, f1);
  #pragma unroll
  for (int p = 1; p < 16; ++p) {
    float f2 = m2 * f1 - f0;
    float f3 = m2 * f2 - f1;
    fb[p] = cvtpk_bf16(f2, f3);
    f0 = f2; f1 = f3;
  }
}

__global__ __launch_bounds__(256, 4) void kan_fft_fallback(
    const float* __restrict__ x, const float* __restrict__ fc,
    const float* __restrict__ bias, const float* __restrict__ mask,
    const float* __restrict__ scale_base, const float* __restrict__ scale_fft,
    float* __restrict__ out)
{
  __shared__ short A_lds[BM * PITCH];
  __shared__ short B_lds[BM * PITCH];

  const int tid = threadIdx.x;
  const int bx  = blockIdx.x;
  const int kc  = bx & 15;
  const int bn  = (bx >> 4) & 1;
  const int bm  = bx >> 5;
  const int i0  = kc * ICH;

  const int lane = tid & 63;
  const int wave = tid >> 6;
  const int wm   = wave & 1;
  const int wn   = wave >> 1;
  const int l15  = lane & 15;
  const int kgrp = (lane >> 4) * 8;

  f4v acc[4][4];
  #pragma unroll
  for (int a = 0; a < 4; ++a)
    #pragma unroll
    for (int b = 0; b < 4; ++b)
      acc[a][b] = (f4v){0.f, 0.f, 0.f, 0.f};

  const int row  = tid >> 1;
  const int half = tid & 1;
  const int mg   = bm * BM + row;
  const int jg   = bn * 128 + row;

  const float* xrow   = x + (size_t)mg * I_DIM + i0;
  const float* fcbase = fc + (size_t)half * (O_DIM * I_DIM * G_DIM)
                           + ((size_t)jg * I_DIM + i0) * G_DIM;
  uint32_t* Arow = (uint32_t*)&A_lds[row * PITCH + half * 32];
  uint32_t* Brow = (uint32_t*)&B_lds[row * PITCH + half * 32];

  for (int it = 0; it < ICH; ++it) {
    __syncthreads();
    {
      uint32_t fb[16];
      gen_feat(xrow[it], half, fb);
      ((uint4*)Arow)[0] = make_uint4(fb[0],  fb[1],  fb[2],  fb[3]);
      ((uint4*)Arow)[1] = make_uint4(fb[4],  fb[5],  fb[6],  fb[7]);
      ((uint4*)Arow)[2] = make_uint4(fb[8],  fb[9],  fb[10], fb[11]);
      ((uint4*)Arow)[3] = make_uint4(fb[12], fb[13], fb[14], fb[15]);
    }
    {
      const int i = i0 + it;
      const size_t ij = (size_t)i * O_DIM + jg;
      const float sf  = scale_fft[ij] * mask[ij];
      const float* src = fcbase + it * G_DIM;
      uint32_t wb[16];
      #pragma unroll
      for (int q = 0; q < 8; ++q) {
        float4 v = ((const float4*)src)[q];
        wb[2*q]   = pack2bf16(v.x * sf, v.y * sf);
        wb[2*q+1] = pack2bf16(v.z * sf, v.w * sf);
      }
      ((uint4*)Brow)[0] = make_uint4(wb[0],  wb[1],  wb[2],  wb[3]);
      ((uint4*)Brow)[1] = make_uint4(wb[4],  wb[5],  wb[6],  wb[7]);
      ((uint4*)Brow)[2] = make_uint4(wb[8],  wb[9],  wb[10], wb[11]);
      ((uint4*)Brow)[3] = make_uint4(wb[12], wb[13], wb[14], wb[15]);
    }
    __syncthreads();
    #pragma unroll
    for (int ks = 0; ks < 2; ++ks) {
      s8v a[4], b[4];
      #pragma unroll
      for (int tm = 0; tm < 4; ++tm)
        a[tm] = *(const s8v*)&A_lds[(wm * 64 + tm * 16 + l15) * PITCH + ks * 32 + kgrp];
      #pragma unroll
      for (int tn = 0; tn < 4; ++tn)
        b[tn] = *(const s8v*)&B_lds[(wn * 64 + tn * 16 + l15) * PITCH + ks * 32 + kgrp];
      #pragma unroll
      for (int tm = 0; tm < 4; ++tm)
        #pragma unroll
        for (int tn = 0; tn < 4; ++tn)
          acc[tm][tn] = __builtin_amdgcn_mfma_f32_16x16x32_bf16(a[tm], b[tn], acc[tm][tn], 0, 0, 0);
    }
  }

  __syncthreads();
  {
    const float* xb = xrow + half * 8;
    float4 v0 = ((const float4*)xb)[0];
    float4 v1 = ((const float4*)xb)[1];
    uint32_t a0 = pack2bf16(silu_f(v0.x), silu_f(v0.y));
    uint32_t a1 = pack2bf16(silu_f(v0.z), silu_f(v0.w));
    uint32_t a2 = pack2bf16(silu_f(v1.x), silu_f(v1.y));
    uint32_t a3 = pack2bf16(silu_f(v1.z), silu_f(v1.w));
    ((uint4*)&A_lds[row * PITCH + half * 8])[0]      = make_uint4(a0, a1, a2, a3);
    ((uint4*)&A_lds[row * PITCH + 16 + half * 8])[0] = make_uint4(0, 0, 0, 0);
    uint32_t w[4];
    #pragma unroll
    for (int p = 0; p < 4; ++p) {
      const int ia = i0 + half * 8 + 2 * p;
      const size_t o0 = (size_t)ia * O_DIM + jg;
      const size_t o1 = o0 + O_DIM;
      w[p] = pack2bf16(scale_base[o0] * mask[o0], scale_base[o1] * mask[o1]);
    }
    ((uint4*)&B_lds[row * PITCH + half * 8])[0]      = make_uint4(w[0], w[1], w[2], w[3]);
    ((uint4*)&B_lds[row * PITCH + 16 + half * 8])[0] = make_uint4(0, 0, 0, 0);
  }
  __syncthreads();
  {
    s8v a[4], b[4];
    #pragma unroll
    for (int tm = 0; tm < 4; ++tm)
      a[tm] = *(const s8v*)&A_lds[(wm * 64 + tm * 16 + l15) * PITCH + kgrp];
    #pragma unroll
    for (int tn = 0; tn < 4; ++tn)
      b[tn] = *(const s8v*)&B_lds[(wn * 64 + tn * 16 + l15) * PITCH + kgrp];
    #pragma unroll
    for (int tm = 0; tm < 4; ++tm)
      #pragma unroll
      for (int tn = 0; tn < 4; ++tn)
        acc[tm][tn] = __builtin_amdgcn_mfma_f32_16x16x32_bf16(a[tm], b[tn], acc[tm][tn], 0, 0, 0);
  }

  const int quad = lane >> 4;
  #pragma unroll
  for (int tm = 0; tm < 4; ++tm) {
    #pragma unroll
    for (int tn = 0; tn < 4; ++tn) {
      const int n_g = bn * 128 + wn * 64 + tn * 16 + l15;
      f4v v = acc[tm][tn];
      #pragma unroll
      for (int r = 0; r < 4; ++r) {
        const int m_g = bm * BM + wm * 64 + tm * 16 + quad * 4 + r;
        float val = v[r];
        if (kc == 0) val += bias[n_g];
        atomicAdd(&out[(size_t)m_g * O_DIM + n_g], val);
      }
    }
  }
}

extern "C" void kernel_launch(void* const* d_in, const int* in_sizes, int n_in,
                              void* d_out, int out_size, void* d_ws, size_t ws_size,
                              hipStream_t stream) {
  const float* x          = (const float*)d_in[0];
  const float* fc         = (const float*)d_in[1];
  const float* bias       = (const float*)d_in[2];
  const float* mask       = (const float*)d_in[3];
  const float* scale_base = (const float*)d_in[4];
  const float* scale_fft  = (const float*)d_in[5];
  float* out = (float*)d_out;

  const size_t BP_B    = (size_t)I_DIM * O_DIM * 64 * 2;        //  8,388,608
  const size_t PARTH_B = (size_t)KSPLIT * B_DIM * O_DIM * 2;    // 33,554,432

  if (ws_size >= BP_B + PARTH_B) {
    short*          Bp      = (short*)d_ws;
    unsigned short* partial = (unsigned short*)((char*)d_ws + BP_B);
    prep_bs_kernel<<<dim3(1024), dim3(256), 0, stream>>>(fc, mask, scale_fft, Bp);
    kan_main9<<<dim3(512), dim3(512), 0, stream>>>(x, Bp, mask, scale_base, partial);
    reduce_kernel<<<dim3(512), dim3(256), 0, stream>>>(partial, bias, out);
  } else {
    hipMemsetAsync(d_out, 0, (size_t)out_size * sizeof(float), stream);
    kan_fft_fallback<<<dim3(1024), dim3(256), 0, stream>>>(
        x, fc, bias, mask, scale_base, scale_fft, out);
  }
}